// Round 2
// baseline (77.755 us; speedup 1.0000x reference)
//
#include <hip/hip_runtime.h>
#include <math.h>

#define NCAND 75
#define NBT 8
#define NC 3
#define IMH 192
#define IMW 192
#define CROP 174
#define CH0 9
#define CW0 9
#define NPIX (CROP * CROP)          // 30276
#define CHW (IMH * IMW)             // 36864
#define IMG_STRIDE (NC * CHW)
#define DENOM 90828.0f              // NC * CROP * CROP
#define ROWS 6                      // rows per block
#define NCHUNK (CROP / ROWS)        // 29
#define NTHREADS 192

// --- kernel 1: per-(cand, row-chunk) SAD partials for ALL 8 images ---------
// cand decomposition: cand = (ih*5 + iw)*3 + ir
//   ash = 2 - ih ; asw = 2 - iw ; arot = (1 - ir) * pi/180
__global__ __launch_bounds__(NTHREADS) void sad_allimg_kernel(
        const float* __restrict__ img,
        const float* __restrict__ ref,
        float* __restrict__ part) {
    const int chunk = blockIdx.x;         // 0..28
    const int cand  = blockIdx.y;         // 0..74

    const int ih  = cand / 15;
    const int rem = cand % 15;
    const int iw  = rem / 3;
    const int ir  = rem % 3;

    const float ash  = (float)(2 - ih);
    const float asw  = (float)(2 - iw);
    const float arot = (float)(1 - ir) * 0.017453292519943295f;
    const float cr = cosf(arot);
    const float sr = sinf(arot);

    const int j = threadIdx.x;            // column in crop
    float acc[NBT];
#pragma unroll
    for (int im = 0; im < NBT; ++im) acc[im] = 0.0f;

    if (j < CROP) {
        const float xx = (float)(CW0 + j);
        const float t1 = (xx + asw) - 95.5f;            // aw - cx (asc==1)

        for (int r = 0; r < ROWS; ++r) {
            const int i = chunk * ROWS + r;
            const float yy = (float)(CH0 + i);
            const float t2 = (yy + ash) - 95.5f;        // ah - cy
            const float awr = cr * t1 - sr * t2;
            const float ahr = sr * t1 + cr * t2;
            const float gx = awr / 95.5f;
            const float gy = ahr / 95.5f;
            const float x = ((gx + 1.0f) * 192.0f - 1.0f) * 0.5f;
            const float y = ((gy + 1.0f) * 192.0f - 1.0f) * 0.5f;

            const float x0f = floorf(x);
            const float y0f = floorf(y);
            const float wx = x - x0f;
            const float wy = y - y0f;
            const int x0 = (int)x0f, y0 = (int)y0f;
            const int x1 = x0 + 1,  y1 = y0 + 1;

            float w00 = (1.0f - wx) * (1.0f - wy);
            float w10 = wx * (1.0f - wy);
            float w01 = (1.0f - wx) * wy;
            float w11 = wx * wy;

            const bool vx0 = (x0 >= 0) & (x0 < IMW);
            const bool vx1 = (x1 >= 0) & (x1 < IMW);
            const bool vy0 = (y0 >= 0) & (y0 < IMH);
            const bool vy1 = (y1 >= 0) & (y1 < IMH);
            if (!(vx0 & vy0)) w00 = 0.0f;
            if (!(vx1 & vy0)) w10 = 0.0f;
            if (!(vx0 & vy1)) w01 = 0.0f;
            if (!(vx1 & vy1)) w11 = 0.0f;

            const int xc0 = min(max(x0, 0), IMW - 1);
            const int xc1 = min(max(x1, 0), IMW - 1);
            const int yc0 = min(max(y0, 0), IMH - 1);
            const int yc1 = min(max(y1, 0), IMH - 1);

            const int a00 = yc0 * IMW + xc0;
            const int a10 = yc0 * IMW + xc1;
            const int a01 = yc1 * IMW + xc0;
            const int a11 = yc1 * IMW + xc1;
            const int ra  = (CH0 + i) * IMW + (CW0 + j);

#pragma unroll
            for (int im = 0; im < NBT; ++im) {
                const float* __restrict__ bi = img + im * IMG_STRIDE;
                const float* __restrict__ br = ref + im * IMG_STRIDE;
                float s = 0.0f;
#pragma unroll
                for (int c = 0; c < NC; ++c) {
                    const float* __restrict__ cb = bi + c * CHW;
                    const float v = w00 * cb[a00] + w10 * cb[a10] +
                                    w01 * cb[a01] + w11 * cb[a11];
                    s += fabsf(v - br[c * CHW + ra]);
                }
                acc[im] += s;
            }
        }
    }

    // reduce each image's accumulator across the block (3 waves)
    __shared__ float wsum[3][NBT];
    const int lane = threadIdx.x & 63;
    const int wid  = threadIdx.x >> 6;
#pragma unroll
    for (int im = 0; im < NBT; ++im) {
        float a = acc[im];
#pragma unroll
        for (int off = 32; off > 0; off >>= 1) a += __shfl_down(a, off, 64);
        if (lane == 0) wsum[wid][im] = a;
    }
    __syncthreads();
    if (threadIdx.x < NBT) {
        const int im = threadIdx.x;
        part[(cand * NCHUNK + chunk) * NBT + im] =
            wsum[0][im] + wsum[1][im] + wsum[2][im];
    }
}

// --- kernel 2: reduce chunks -> sad, then per-image argmin -----------------
__global__ __launch_bounds__(640) void finalize_ws(const float* __restrict__ part,
                                                   float* __restrict__ out) {
    __shared__ float sads[NCAND * NBT];
    const int t = threadIdx.x;
    if (t < NCAND * NBT) {
        const int cand = t / NBT;
        const int im   = t % NBT;
        float ssum = 0.0f;
        const float* p = part + cand * NCHUNK * NBT + im;
        for (int ch = 0; ch < NCHUNK; ++ch) ssum += p[ch * NBT];
        const float sv = ssum / DENOM;
        sads[t] = sv;
        out[t] = sv;
    }
    __syncthreads();
    if (t < NBT) {
        float best = sads[t];
        int bi = 0;
        for (int c2 = 1; c2 < NCAND; ++c2) {
            const float v = sads[c2 * NBT + t];
            if (v < best) { best = v; bi = c2; }   // strict <: first-min tie-break
        }
        const int i0 = bi / 15;
        const int r  = bi % 15;
        const int i1 = r / 3;
        const int i2 = r % 3;
        out[600 + 0 * NBT + t] = (float)i0;
        out[600 + 1 * NBT + t] = (float)i1;
        out[600 + 2 * NBT + t] = (float)i2;
        out[600 + 3 * NBT + t] = 0.0f;
    }
}

// ---------------- fallback (tiny ws): round-0 direct path ------------------
__global__ __launch_bounds__(256) void sad_direct_kernel(const float* __restrict__ img,
                                                         const float* __restrict__ ref,
                                                         float* __restrict__ out) {
    const int ci  = blockIdx.x;
    const int cand = ci / NBT;
    const int im   = ci % NBT;
    const int ih  = cand / 15;
    const int rem = cand % 15;
    const int iw  = rem / 3;
    const int ir  = rem % 3;
    const float ash  = (float)(2 - ih);
    const float asw  = (float)(2 - iw);
    const float arot = (float)(1 - ir) * 0.017453292519943295f;
    const float cr = cosf(arot);
    const float sr = sinf(arot);
    const float* ib = img + im * IMG_STRIDE;
    const float* rb = ref + im * IMG_STRIDE;
    float acc = 0.0f;
    for (int p = (int)threadIdx.x; p < NPIX; p += 256) {
        const int i = p / CROP;
        const int j = p - i * CROP;
        const float xx = (float)(CW0 + j);
        const float yy = (float)(CH0 + i);
        const float t1 = (xx + asw) - 95.5f;
        const float t2 = (yy + ash) - 95.5f;
        const float awr = cr * t1 - sr * t2;
        const float ahr = sr * t1 + cr * t2;
        const float gx = awr / 95.5f;
        const float gy = ahr / 95.5f;
        const float x = ((gx + 1.0f) * 192.0f - 1.0f) * 0.5f;
        const float y = ((gy + 1.0f) * 192.0f - 1.0f) * 0.5f;
        const float x0f = floorf(x);
        const float y0f = floorf(y);
        const float wx = x - x0f;
        const float wy = y - y0f;
        const int x0 = (int)x0f, y0 = (int)y0f;
        const int x1 = x0 + 1,  y1 = y0 + 1;
        float w00 = (1.0f - wx) * (1.0f - wy);
        float w10 = wx * (1.0f - wy);
        float w01 = (1.0f - wx) * wy;
        float w11 = wx * wy;
        const bool vx0 = (x0 >= 0) & (x0 < IMW);
        const bool vx1 = (x1 >= 0) & (x1 < IMW);
        const bool vy0 = (y0 >= 0) & (y0 < IMH);
        const bool vy1 = (y1 >= 0) & (y1 < IMH);
        if (!(vx0 & vy0)) w00 = 0.0f;
        if (!(vx1 & vy0)) w10 = 0.0f;
        if (!(vx0 & vy1)) w01 = 0.0f;
        if (!(vx1 & vy1)) w11 = 0.0f;
        const int xc0 = min(max(x0, 0), IMW - 1);
        const int xc1 = min(max(x1, 0), IMW - 1);
        const int yc0 = min(max(y0, 0), IMH - 1);
        const int yc1 = min(max(y1, 0), IMH - 1);
        const int a00 = yc0 * IMW + xc0;
        const int a10 = yc0 * IMW + xc1;
        const int a01 = yc1 * IMW + xc0;
        const int a11 = yc1 * IMW + xc1;
        const int ra  = (CH0 + i) * IMW + (CW0 + j);
#pragma unroll
        for (int c = 0; c < NC; ++c) {
            const float* cb = ib + c * CHW;
            const float v = w00 * cb[a00] + w10 * cb[a10] +
                            w01 * cb[a01] + w11 * cb[a11];
            acc += fabsf(v - rb[c * CHW + ra]);
        }
    }
#pragma unroll
    for (int off = 32; off > 0; off >>= 1) acc += __shfl_down(acc, off, 64);
    __shared__ float wsum[4];
    const int lane = threadIdx.x & 63;
    const int wid  = threadIdx.x >> 6;
    if (lane == 0) wsum[wid] = acc;
    __syncthreads();
    if (threadIdx.x == 0)
        out[ci] = (wsum[0] + wsum[1] + wsum[2] + wsum[3]) / DENOM;
}

__global__ __launch_bounds__(64) void finalize_direct(float* __restrict__ out) {
    const int t = threadIdx.x;
    if (t < NBT) {
        float best = out[t];
        int bi = 0;
        for (int c2 = 1; c2 < NCAND; ++c2) {
            const float v = out[c2 * NBT + t];
            if (v < best) { best = v; bi = c2; }
        }
        const int i0 = bi / 15;
        const int r  = bi % 15;
        const int i1 = r / 3;
        const int i2 = r % 3;
        out[600 + 0 * NBT + t] = (float)i0;
        out[600 + 1 * NBT + t] = (float)i1;
        out[600 + 2 * NBT + t] = (float)i2;
        out[600 + 3 * NBT + t] = 0.0f;
    }
}

extern "C" void kernel_launch(void* const* d_in, const int* in_sizes, int n_in,
                              void* d_out, int out_size, void* d_ws, size_t ws_size,
                              hipStream_t stream) {
    const float* img = (const float*)d_in[0];
    const float* ref = (const float*)d_in[1];
    float* out = (float*)d_out;

    if (ws_size >= (size_t)(NCAND * NCHUNK * NBT * sizeof(float))) {
        float* part = (float*)d_ws;
        hipLaunchKernelGGL(sad_allimg_kernel, dim3(NCHUNK, NCAND), dim3(NTHREADS),
                           0, stream, img, ref, part);
        hipLaunchKernelGGL(finalize_ws, dim3(1), dim3(640), 0, stream, part, out);
    } else {
        hipLaunchKernelGGL(sad_direct_kernel, dim3(NCAND * NBT), dim3(256),
                           0, stream, img, ref, out);
        hipLaunchKernelGGL(finalize_direct, dim3(1), dim3(64), 0, stream, out);
    }
}